// Round 3
// baseline (285.275 us; speedup 1.0000x reference)
//
#include <hip/hip_runtime.h>
#include <cstdint>

#define D_EDGES 64
#define K_KEEP  32

// Bit-exact replication of numpy's SIMD f32 exp (Cephes-based
// simd_exp_FLOAT from loops_exponent_log.dispatch.c.src, max ULP 2.52).
// Valid for |x| well inside [-87, 88]; our logits are ~N(0,1).
// All fmaf -> v_fma_f32 (IEEE exact), matching _mm512_fmadd_ps lanes.
__device__ __forceinline__ float np_expf(float x) {
    const float log2e     = 1.44269504088896341f;   // -> 0x3FB8AA3B
    const float cvt_magic = 12582912.0f;            // 1.5 * 2^23, RNE rounding trick
    const float neg_ln2hi = -0.693359375f;
    const float neg_ln2lo = 2.12194440e-4f;
    const float p0 = 1.9875691500E-4f;
    const float p1 = 1.3981999507E-3f;
    const float p2 = 8.3334519073E-3f;
    const float p3 = 4.1665795894E-2f;
    const float p4 = 1.6666665459E-1f;
    const float p5 = 5.0000001201E-1f;

    float q = fmaf(x, log2e, cvt_magic);            // round(x*log2e) via magic
    q -= cvt_magic;                                 // exact integer-valued f32
    x = fmaf(q, neg_ln2hi, x);                      // two-term range reduction
    x = fmaf(q, neg_ln2lo, x);
    float x2 = x * x;
    float poly = fmaf(p0, x, p1);
    poly = fmaf(poly, x, p2);
    poly = fmaf(poly, x, p3);
    poly = fmaf(poly, x, p4);
    poly = fmaf(poly, x, p5);
    poly = fmaf(poly, x2, x);
    poly = poly + 1.0f;
    return ldexpf(poly, (int)q);                    // == scalef for in-range q
}

__device__ __forceinline__ float sigmoid_np(float x) {
    float e = np_expf(-x);          // np.exp(-logits), numpy SIMD path
    return 1.0f / (1.0f + e);       // IEEE f32 add + correctly-rounded div
}

__global__ void sigmoid_kernel(const float* __restrict__ logits,
                               float* __restrict__ s, int n) {
    int i = blockIdx.x * blockDim.x + threadIdx.x;
    if (i < n) s[i] = sigmoid_np(logits[i]);
}

// One wave (64 lanes) per segment of D=64 edges.
// Key = (f32bits(sim) << 6) | (63 ^ lane). sim in (0,1] so f32 bits are
// monotone; low 6 bits give "ties -> lower index first" under a DESCENDING
// sort (jax.lax.top_k semantics).
template <bool USE_TABLE>
__global__ void topk_kernel(const int* __restrict__ edge_index,  // [2, E]
                            const float* __restrict__ s,
                            const float* __restrict__ logits,
                            int* __restrict__ out,               // [2, nseg*K]
                            long long E, long long nseg) {
    long long gtid = (long long)blockIdx.x * blockDim.x + threadIdx.x;
    long long w = gtid >> 6;          // segment id (one wave per segment)
    int lane = (int)(gtid & 63);
    if (w >= nseg) return;

    long long e = w * D_EDGES + lane;
    int src = edge_index[e];
    int dst = edge_index[E + e];

    float ss, sd;
    if (USE_TABLE) {
        ss = s[src];                  // random gather, 1MB table (L2-resident)
        sd = s[dst];
    } else {
        ss = sigmoid_np(logits[src]);
        sd = sigmoid_np(logits[dst]);
    }
    float sim = 1.0f - fabsf(ss - sd);   // matches np f32: 1.0 - |e0 - e1|

    unsigned long long key =
        ((unsigned long long)__float_as_uint(sim) << 6) |
        (unsigned long long)(lane ^ 63);

    // Full 64-lane bitonic sort, descending (rank 0 = largest key at lane 0).
    // Keys all distinct (lane index embedded) -> strict total order.
#pragma unroll
    for (int k = 2; k <= 64; k <<= 1) {
#pragma unroll
        for (int j = k >> 1; j > 0; j >>= 1) {
            unsigned long long other = __shfl_xor(key, j, 64);
            bool up = ((lane & k) == 0);        // descending sub-block
            bool isLower = ((lane & j) == 0);
            bool mine_first = key > other;
            if (mine_first != (isLower == up)) key = other;
        }
    }

    // Lane r (r < K) holds rank-r key; recover the owning lane and pull its
    // (src, dst). All lanes shuffle; only lanes < K store.
    int origLane = ((int)(key & 63)) ^ 63;
    int sel_src = __shfl(src, origLane, 64);
    int sel_dst = __shfl(dst, origLane, 64);

    if (lane < K_KEEP) {
        long long base = w * K_KEEP + lane;
        out[base] = sel_src;                       // row 0: src selections
        out[nseg * K_KEEP + base] = sel_dst;       // row 1: dst selections
    }
}

extern "C" void kernel_launch(void* const* d_in, const int* in_sizes, int n_in,
                              void* d_out, int out_size, void* d_ws, size_t ws_size,
                              hipStream_t stream) {
    const float* logits = (const float*)d_in[0];
    const int* edge_index = (const int*)d_in[1];
    int N = in_sizes[0];
    long long E = (long long)in_sizes[1] / 2;
    long long nseg = E / D_EDGES;
    int* out = (int*)d_out;

    long long total_threads = nseg * 64;
    int blocks = (int)((total_threads + 255) / 256);

    if (ws_size >= (size_t)N * sizeof(float)) {
        float* s = (float*)d_ws;
        sigmoid_kernel<<<(N + 255) / 256, 256, 0, stream>>>(logits, s, N);
        topk_kernel<true><<<blocks, 256, 0, stream>>>(edge_index, s, logits, out, E, nseg);
    } else {
        topk_kernel<false><<<blocks, 256, 0, stream>>>(edge_index, nullptr, logits, out, E, nseg);
    }
}

// Round 4
// 270.285 us; speedup vs baseline: 1.0555x; 1.0555x over previous
//
#include <hip/hip_runtime.h>
#include <cstdint>

#define D_EDGES 64
#define K_KEEP  32

// Bit-exact replication of numpy's SIMD f32 exp (Cephes-based, max ULP 2.52).
// Verified: absmax 0 vs the np reference in round 3.
__device__ __forceinline__ float np_expf(float x) {
    const float log2e     = 1.44269504088896341f;
    const float cvt_magic = 12582912.0f;            // 1.5 * 2^23 RNE trick
    const float neg_ln2hi = -0.693359375f;
    const float neg_ln2lo = 2.12194440e-4f;
    const float p0 = 1.9875691500E-4f;
    const float p1 = 1.3981999507E-3f;
    const float p2 = 8.3334519073E-3f;
    const float p3 = 4.1665795894E-2f;
    const float p4 = 1.6666665459E-1f;
    const float p5 = 5.0000001201E-1f;

    float q = fmaf(x, log2e, cvt_magic);
    q -= cvt_magic;
    x = fmaf(q, neg_ln2hi, x);
    x = fmaf(q, neg_ln2lo, x);
    float x2 = x * x;
    float poly = fmaf(p0, x, p1);
    poly = fmaf(poly, x, p2);
    poly = fmaf(poly, x, p3);
    poly = fmaf(poly, x, p4);
    poly = fmaf(poly, x, p5);
    poly = fmaf(poly, x2, x);
    poly = poly + 1.0f;
    return ldexpf(poly, (int)q);
}

__device__ __forceinline__ float sigmoid_np(float x) {
    float e = np_expf(-x);
    return 1.0f / (1.0f + e);
}

__global__ void sigmoid_kernel(const float* __restrict__ logits,
                               float* __restrict__ s, int n) {
    int i = blockIdx.x * blockDim.x + threadIdx.x;
    if (i < n) s[i] = sigmoid_np(logits[i]);
}

// ---- xor-shuffle of a u64, routed to the cheapest HW path per distance ----
// j=1,2 -> DPP quad_perm; j=8 -> DPP row_ror:8 (== xor8 within 16-lane rows);
// j=4,16 -> ds_swizzle (no index VGPR, cheaper than bpermute);
// j=32 -> __shfl_xor (crosses the 32-lane swizzle boundary).
template <int CTRL>
__device__ __forceinline__ unsigned long long xor_dpp_u64(unsigned long long v) {
    int lo = (int)(unsigned)v;
    int hi = (int)(v >> 32);
    lo = __builtin_amdgcn_update_dpp(lo, lo, CTRL, 0xF, 0xF, true);
    hi = __builtin_amdgcn_update_dpp(hi, hi, CTRL, 0xF, 0xF, true);
    return ((unsigned long long)(unsigned)hi << 32) | (unsigned)lo;
}

template <int OFF>
__device__ __forceinline__ unsigned long long xor_swz_u64(unsigned long long v) {
    int lo = (int)(unsigned)v;
    int hi = (int)(v >> 32);
    lo = __builtin_amdgcn_ds_swizzle(lo, OFF);
    hi = __builtin_amdgcn_ds_swizzle(hi, OFF);
    return ((unsigned long long)(unsigned)hi << 32) | (unsigned)lo;
}

template <int J>
__device__ __forceinline__ unsigned long long xorshfl_u64(unsigned long long v) {
    if constexpr (J == 1)       return xor_dpp_u64<0xB1>(v);    // quad_perm [1,0,3,2]
    else if constexpr (J == 2)  return xor_dpp_u64<0x4E>(v);    // quad_perm [2,3,0,1]
    else if constexpr (J == 4)  return xor_swz_u64<0x101F>(v);  // swizzle xor4
    else if constexpr (J == 8)  return xor_dpp_u64<0x128>(v);   // row_ror:8 == xor8
    else if constexpr (J == 16) return xor_swz_u64<0x401F>(v);  // swizzle xor16
    else {                                                      // J == 32
        int lo = (int)(unsigned)v;
        int hi = (int)(v >> 32);
        lo = __shfl_xor(lo, 32, 64);
        hi = __shfl_xor(hi, 32, 64);
        return ((unsigned long long)(unsigned)hi << 32) | (unsigned)lo;
    }
}

// One bitonic compare-exchange substage, descending overall.
// Semantics identical to the verified round-3 loop body.
template <int K, int J>
__device__ __forceinline__ void stage(unsigned long long& key, int lane) {
    unsigned long long other = xorshfl_u64<J>(key);
    bool up = (lane & K) == 0;
    bool isLower = (lane & J) == 0;
    bool mine_first = key > other;
    if (mine_first != (isLower == up)) key = other;
}

// One wave (64 lanes) per segment of D=64 edges.
// Key = (f32bits(sim) << 6) | (63 ^ lane): f32 bits monotone for sim in (0,1];
// low bits give "ties -> lower index first" under a DESCENDING sort
// (jax.lax.top_k semantics). Verified absmax=0 in round 3.
template <bool USE_TABLE>
__global__ void topk_kernel(const int* __restrict__ edge_index,  // [2, E]
                            const float* __restrict__ s,
                            const float* __restrict__ logits,
                            int* __restrict__ out,               // [2, nseg*K]
                            long long E, long long nseg) {
    long long gtid = (long long)blockIdx.x * blockDim.x + threadIdx.x;
    long long w = gtid >> 6;          // segment id (one wave per segment)
    int lane = (int)(gtid & 63);
    if (w >= nseg) return;

    long long e = w * D_EDGES + lane;
    int src = edge_index[e];
    int dst = edge_index[E + e];

    float ss, sd;
    if (USE_TABLE) {
        ss = s[src];                  // random gather, 1MB table (L2-resident)
        sd = s[dst];                  // wave-uniform -> broadcast
    } else {
        ss = sigmoid_np(logits[src]);
        sd = sigmoid_np(logits[dst]);
    }
    float sim = 1.0f - fabsf(ss - sd);

    unsigned long long key =
        ((unsigned long long)__float_as_uint(sim) << 6) |
        (unsigned long long)(lane ^ 63);

    // Full 64-lane bitonic sort, descending; 14/21 substages on DPP (VALU),
    // only j=4,16,32 touch the DS pipe.
    stage<2, 1>(key, lane);
    stage<4, 2>(key, lane);   stage<4, 1>(key, lane);
    stage<8, 4>(key, lane);   stage<8, 2>(key, lane);   stage<8, 1>(key, lane);
    stage<16, 8>(key, lane);  stage<16, 4>(key, lane);  stage<16, 2>(key, lane);
    stage<16, 1>(key, lane);
    stage<32, 16>(key, lane); stage<32, 8>(key, lane);  stage<32, 4>(key, lane);
    stage<32, 2>(key, lane);  stage<32, 1>(key, lane);
    stage<64, 32>(key, lane); stage<64, 16>(key, lane); stage<64, 8>(key, lane);
    stage<64, 4>(key, lane);  stage<64, 2>(key, lane);  stage<64, 1>(key, lane);

    // Lane r (r < K) holds rank-r key; pull the owning lane's (src, dst).
    int origLane = ((int)(key & 63)) ^ 63;
    int sel_src = __shfl(src, origLane, 64);
    int sel_dst = __shfl(dst, origLane, 64);

    if (lane < K_KEEP) {
        long long base = w * K_KEEP + lane;
        out[base] = sel_src;                       // row 0: src selections
        out[nseg * K_KEEP + base] = sel_dst;       // row 1: dst selections
    }
}

extern "C" void kernel_launch(void* const* d_in, const int* in_sizes, int n_in,
                              void* d_out, int out_size, void* d_ws, size_t ws_size,
                              hipStream_t stream) {
    const float* logits = (const float*)d_in[0];
    const int* edge_index = (const int*)d_in[1];
    int N = in_sizes[0];
    long long E = (long long)in_sizes[1] / 2;
    long long nseg = E / D_EDGES;
    int* out = (int*)d_out;

    long long total_threads = nseg * 64;
    int blocks = (int)((total_threads + 255) / 256);

    if (ws_size >= (size_t)N * sizeof(float)) {
        float* s = (float*)d_ws;
        sigmoid_kernel<<<(N + 255) / 256, 256, 0, stream>>>(logits, s, N);
        topk_kernel<true><<<blocks, 256, 0, stream>>>(edge_index, s, logits, out, E, nseg);
    } else {
        topk_kernel<false><<<blocks, 256, 0, stream>>>(edge_index, nullptr, logits, out, E, nseg);
    }
}